// Round 7
// baseline (327.968 us; speedup 1.0000x reference)
//
#include <hip/hip_runtime.h>
#include <hip/hip_bf16.h>
#include <cstdint>
#include <cstddef>

// WideLSTM: N=32 blocks, I=64, H=128, B=16, T=256.
// TWO-KERNEL SPLIT:
//  Kernel A (gx_gemm, 512 WGs x 512 thr): gx[(n,b)][t][h][4gates] =
//    bias_ih + bias_hh + Wih * x  — dense GEMM at MFMA efficiency (~4us of
//    matrix work + 268MB write).  Gate-interleaved A-tiles: lane acc f32x4 =
//    4 gates of one (h,t) -> single dwordx4 store.
//  Kernel B (wide_lstm_pc, 128 WGs x 1024 thr = 16 waves): R2 K-split pair
//    skeleton, Whh only (MFMA pole 930 -> 620 cyc/SIMD):
//      wave w (0..7):  Whh k[0,64),  2-deep chains, epilogue owner.
//      wave w+8:       Whh k[64,128) + gx consume (4-deep register ring of
//                      dwordx4 loads, issued 4 steps ahead; partner has NO
//                      stores so vmcnt stays clean — R4 lesson), partial
//                      (incl. gx) pre-selected -> pbuf.
//    2 lgkm-only barriers/step; no xbuf, no x staging, no helper MFMAs.
// d_ws holds gx (268MB); if ws_size too small, fall back to verbatim R2.

#define TSTEPS 256

typedef float  f32x4  __attribute__((ext_vector_type(4)));
typedef float  f32x2  __attribute__((ext_vector_type(2)));
typedef __bf16 bf16x8 __attribute__((ext_vector_type(8)));
typedef short  s16x8  __attribute__((ext_vector_type(8)));

union Frag { s16x8 s; bf16x8 b; };

#define KSIG -1.4426950408889634f   // -1/ln2 (sigmoid)
#define KTAN  2.8853900817779268f   //  2/ln2 (tanh)

__device__ __forceinline__ short f2bf(float f) {
  uint32_t u = __builtin_bit_cast(uint32_t, f);
  u += 0x7fffu + ((u >> 16) & 1u);
  return (short)(u >> 16);
}

__device__ __forceinline__ void sync_lds() {
  asm volatile("s_waitcnt lgkmcnt(0)" ::: "memory");
  __builtin_amdgcn_s_barrier();
  asm volatile("" ::: "memory");
}

__device__ __forceinline__ float sig2(float z) {   // rcp(1 + exp2(z))
  return __builtin_amdgcn_rcpf(1.f + __builtin_amdgcn_exp2f(z));
}

__device__ __forceinline__ f32x4 mf(const Frag a, const Frag bb, f32x4 c) {
  return __builtin_amdgcn_mfma_f32_16x16x32_bf16(a.b, bb.b, c, 0, 0, 0);
}

__device__ __forceinline__ float sel4(const f32x4 a, bool m1, bool m2) {
  const float u01 = m1 ? a[1] : a[0];
  const float u23 = m1 ? a[3] : a[2];
  return m2 ? u23 : u01;
}

// ================= Kernel A: gx = bias + Wih * x =================
// grid 512 = (n<<4)|b, 512 thr = 8 waves.  Wave v: h in [16v, 16v+16)
// as 4 gate-interleaved tiles (4h x 4gates).  B cols = 16 timesteps.
__global__ __launch_bounds__(512, 2) void gx_gemm(
    const float* __restrict__ x,   const float* __restrict__ wih,
    const float* __restrict__ bih, const float* __restrict__ bhh,
    float* __restrict__ gx)
{
  const int n    = blockIdx.x >> 4;
  const int b    = blockIdx.x & 15;
  const int tid  = threadIdx.x;
  const int v    = tid >> 6;             // wave 0..7
  const int lane = tid & 63;
  const int col  = lane & 15;            // timestep within 16-chunk
  const int quad = lane >> 4;

  // weights, gate-interleaved rows: tile tt row rr=col ->
  // g = 128*(col&3) + 16v + 4tt + (col>>2); k = 32s + 8*quad + jj
  Frag wA[4][2];
#pragma unroll
  for (int tt = 0; tt < 4; ++tt) {
    const int g = 128 * (col & 3) + 16 * v + 4 * tt + (col >> 2);
#pragma unroll
    for (int s = 0; s < 2; ++s) {
      const float* p = wih + (size_t)(n * 512 + g) * 64 + 32 * s + quad * 8;
      const f32x4 lo = *(const f32x4*)p;
      const f32x4 hi = *(const f32x4*)(p + 4);
      Frag f;
      f.s[0]=f2bf(lo[0]); f.s[1]=f2bf(lo[1]); f.s[2]=f2bf(lo[2]); f.s[3]=f2bf(lo[3]);
      f.s[4]=f2bf(hi[0]); f.s[5]=f2bf(hi[1]); f.s[6]=f2bf(hi[2]); f.s[7]=f2bf(hi[3]);
      wA[tt][s] = f;
    }
  }
  // bias in acc layout: cb[tt][r] for h = 16v + 4tt + quad, gate r
  f32x4 cb[4];
#pragma unroll
  for (int tt = 0; tt < 4; ++tt)
#pragma unroll
    for (int r = 0; r < 4; ++r) {
      const int g2 = n * 512 + 128 * r + 16 * v + 4 * tt + quad;
      cb[tt][r] = bih[g2] + bhh[g2];
    }

  float* gout = gx + (size_t)(n * 16 + b) * 256 * 512;
#pragma unroll 2
  for (int it = 0; it < 16; ++it) {
    const int t = 16 * it + col;
    const float* xp = x + ((size_t)b * 256 + t) * 2048 + n * 64;
    const f32x4 a0 = *(const f32x4*)(xp + 8 * quad);
    const f32x4 a1 = *(const f32x4*)(xp + 8 * quad + 4);
    const f32x4 a2 = *(const f32x4*)(xp + 32 + 8 * quad);
    const f32x4 a3 = *(const f32x4*)(xp + 36 + 8 * quad);
    Frag xf0, xf1;
#pragma unroll
    for (int r = 0; r < 4; ++r) {
      xf0.s[r]     = f2bf(a0[r]);
      xf0.s[4 + r] = f2bf(a1[r]);
      xf1.s[r]     = f2bf(a2[r]);
      xf1.s[4 + r] = f2bf(a3[r]);
    }
#pragma unroll
    for (int tt = 0; tt < 4; ++tt) {
      const f32x4 ac = mf(wA[tt][1], xf1, mf(wA[tt][0], xf0, cb[tt]));
      *(f32x4*)(gout + (size_t)t * 512 + (16 * v + 4 * tt + quad) * 4) = ac;
    }
  }
}

// ================= Kernel B: recurrence, Whh only =================
__global__ __launch_bounds__(1024, 2) void wide_lstm_pc(
    const float* __restrict__ h0,  const float* __restrict__ c0,
    const float* __restrict__ whh, const float* __restrict__ gx,
    float* __restrict__ out)
{
  const int n    = blockIdx.x & 31;
  const int bg   = blockIdx.x >> 5;
  const int tid  = threadIdx.x;
  const int wv   = tid >> 6;             // wave 0..15
  const int w    = wv & 7;               // pair id / h-tile [16w, 16w+16)
  const bool isw = (wv < 8);
  const int lane = tid & 63;
  const int col  = lane & 15;
  const int quad = lane >> 4;
  const int b4   = col & 3;
  const int e2   = col >> 2;
  const int hloc = 4 * quad + e2;
  const int hgl  = 16 * w + hloc;
  const int b    = 4 * bg + b4;

  __shared__ alignas(16) short hbuf[2][4 * 144];
  __shared__ alignas(16) float pbuf[8][64][4];

  // Whh fragments: w: k0 = 32*sl; partner: k0 = 64 + 32*sl (sl=0,1)
  Frag wfr[2][4];
#pragma unroll
  for (int j = 0; j < 4; ++j) {
    const int g = 128 * j + 16 * w + col;
#pragma unroll
    for (int sl = 0; sl < 2; ++sl) {
      const int k0 = (isw ? 32 * sl : 64 + 32 * sl) + quad * 8;
      const float* p = whh + (size_t)(n * 512 + g) * 128 + k0;
      const f32x4 lo = *(const f32x4*)p;
      const f32x4 hi = *(const f32x4*)(p + 4);
      Frag f;
      f.s[0]=f2bf(lo[0]); f.s[1]=f2bf(lo[1]); f.s[2]=f2bf(lo[2]); f.s[3]=f2bf(lo[3]);
      f.s[4]=f2bf(hi[0]); f.s[5]=f2bf(hi[1]); f.s[6]=f2bf(hi[2]); f.s[7]=f2bf(hi[3]);
      wfr[sl][j] = f;
    }
  }

  const int hoff  = b4 * 144 + quad * 8;
  const int hwoff = b4 * 144 + hgl;
  const bool m1 = (e2 & 1), m2 = (e2 & 2);
  const f32x4 kzero = (f32x4){0.f, 0.f, 0.f, 0.f};

  if (isw) {
    // ---------------- epilogue-owner waves ----------------
    if (tid < 256) {
      const int bi = tid >> 6, j2 = (tid & 63) * 2;
      const f32x2 hv = *(const f32x2*)(h0 + (size_t)(4 * bg + bi) * 4096 + n * 128 + j2);
      *(uint32_t*)&hbuf[0][bi * 144 + j2] =
          (uint32_t)(uint16_t)f2bf(hv[0]) | ((uint32_t)(uint16_t)f2bf(hv[1]) << 16);
    }
    float cg = c0[(size_t)b * 4096 + n * 128 + hgl];
    float* outp = out + (size_t)b * (TSTEPS * 4096) + n * 128 + hgl;
    float ho = 0.f;
    __syncthreads();

#define WSTEP(CUR, NXT)                                                      \
  {                                                                          \
    Frag hf0, hf1;                                                           \
    hf0.s = *(const s16x8*)&hbuf[CUR][hoff];                                 \
    hf1.s = *(const s16x8*)&hbuf[CUR][hoff + 32];                            \
    f32x4 ac1[4];                                                            \
    _Pragma("unroll") for (int j = 0; j < 4; ++j)                            \
      ac1[j] = mf(wfr[1][j], hf1, mf(wfr[0][j], hf0, kzero));                \
    float pre[4];                                                            \
    _Pragma("unroll") for (int j = 0; j < 4; ++j)                            \
      pre[j] = sel4(ac1[j], m1, m2);                                         \
    sync_lds(); /* B: partner partial (incl gx) ready */                     \
    const f32x4 vv = *(const f32x4*)&pbuf[w][lane][0];                       \
    pre[0] += vv[0]; pre[1] += vv[1]; pre[2] += vv[2]; pre[3] += vv[3];      \
    const float si = sig2(KSIG * pre[0]);                                    \
    const float sf = sig2(KSIG * pre[1]);                                    \
    const float sg = sig2(KTAN * pre[2]);                                    \
    const float so = sig2(KSIG * pre[3]);                                    \
    float cn = __builtin_fmaf(sf, cg, si);                                   \
    cn = __builtin_fmaf(-2.f, si * sg, cn);                                  \
    cg = cn;                                                                 \
    ho = so * __builtin_fmaf(-2.f, sig2(KTAN * cn), 1.f);                    \
    hbuf[NXT][hwoff] = f2bf(ho);                                             \
    *outp = ho;                                                              \
    outp += 4096;                                                            \
    sync_lds(); /* A' */                                                     \
  }
    for (int t = 0; t < TSTEPS; t += 4) {
      WSTEP(0, 1); WSTEP(1, 0); WSTEP(0, 1); WSTEP(1, 0);
    }
#undef WSTEP
    out[16777216 +         (size_t)b * 4096 + n * 128 + hgl] = ho;
    out[16777216 + 65536 + (size_t)b * 4096 + n * 128 + hgl] = cg;

  } else {
    // ---------------- partner waves (k[64,128) + gx) ----------------
    const float* gp = gx + (size_t)(n * 16 + b) * 256 * 512 + hgl * 4;
    f32x4 g0 = *(const f32x4*)(gp);
    f32x4 g1 = *(const f32x4*)(gp + 512);
    f32x4 g2 = *(const f32x4*)(gp + 1024);
    f32x4 g3 = *(const f32x4*)(gp + 1536);
    __syncthreads();

#define PSTEP(CUR, NXT, S, GX)                                               \
  {                                                                          \
    Frag hf2, hf3;                                                           \
    hf2.s = *(const s16x8*)&hbuf[CUR][hoff + 64];                            \
    hf3.s = *(const s16x8*)&hbuf[CUR][hoff + 96];                            \
    f32x4 ac[4];                                                             \
    _Pragma("unroll") for (int j = 0; j < 4; ++j)                            \
      ac[j] = mf(wfr[1][j], hf3, mf(wfr[0][j], hf2, kzero));                 \
    f32x4 vv;                                                                \
    vv[0] = sel4(ac[0], m1, m2) + GX[0];                                     \
    vv[1] = sel4(ac[1], m1, m2) + GX[1];                                     \
    vv[2] = sel4(ac[2], m1, m2) + GX[2];                                     \
    vv[3] = sel4(ac[3], m1, m2) + GX[3];                                     \
    *(f32x4*)&pbuf[w][lane][0] = vv;                                         \
    {                                                                        \
      const int tt = ((S) + 4 < TSTEPS) ? (S) + 4 : (TSTEPS - 1);            \
      GX = *(const f32x4*)(gp + (size_t)tt * 512);                           \
    }                                                                        \
    sync_lds(); /* B */                                                      \
    sync_lds(); /* A' */                                                     \
  }
    for (int t = 0; t < TSTEPS; t += 4) {
      PSTEP(0, 1, t,     g0);
      PSTEP(1, 0, t + 1, g1);
      PSTEP(0, 1, t + 2, g2);
      PSTEP(1, 0, t + 3, g3);
    }
#undef PSTEP
  }
}

// ================= Fallback: verbatim R2 (ws too small) =================
__global__ __launch_bounds__(1024, 4) void wide_lstm_fb(
    const float* __restrict__ x,   const float* __restrict__ h0,
    const float* __restrict__ c0,  const float* __restrict__ wih,
    const float* __restrict__ whh, const float* __restrict__ bih,
    const float* __restrict__ bhh, float* __restrict__ out)
{
  const int n    = blockIdx.x & 31;
  const int bg   = blockIdx.x >> 5;
  const int tid  = threadIdx.x;
  const int wv   = tid >> 6;
  const int w    = wv & 7;
  const bool isw = (wv < 8);
  const int lane = tid & 63;
  const int col  = lane & 15;
  const int quad = lane >> 4;
  const int b4   = col & 3;
  const int e2   = col >> 2;
  const int hloc = 4 * quad + e2;
  const int hgl  = 16 * w + hloc;
  const int b    = 4 * bg + b4;

  __shared__ alignas(16) short hbuf[2][4 * 144];
  __shared__ alignas(16) short xbuf[2][4 * 96];
  __shared__ alignas(16) float pbuf[8][64][4];

  Frag wfr[3][4];
#pragma unroll
  for (int j = 0; j < 4; ++j) {
    const int g = 128 * j + 16 * w + col;
#pragma unroll
    for (int sl = 0; sl < 3; ++sl) {
      const int s = isw ? sl : sl + 3;
      const int k0 = 32 * s + quad * 8;
      const float* p = (s < 2) ? (wih + (size_t)(n * 512 + g) * 64  + k0)
                               : (whh + (size_t)(n * 512 + g) * 128 + (k0 - 64));
      const f32x4 lo = *(const f32x4*)p;
      const f32x4 hi = *(const f32x4*)(p + 4);
      Frag f;
      f.s[0]=f2bf(lo[0]); f.s[1]=f2bf(lo[1]); f.s[2]=f2bf(lo[2]); f.s[3]=f2bf(lo[3]);
      f.s[4]=f2bf(hi[0]); f.s[5]=f2bf(hi[1]); f.s[6]=f2bf(hi[2]); f.s[7]=f2bf(hi[3]);
      wfr[sl][j] = f;
    }
  }

  const int hoff  = b4 * 144 + quad * 8;
  const int hwoff = b4 * 144 + hgl;
  const int xoff  = b4 * 96  + quad * 8;
  const bool m1 = (e2 & 1), m2 = (e2 & 2);
  const f32x4 kzero = (f32x4){0.f, 0.f, 0.f, 0.f};

  f32x4 cb[4], acpre[4];
  float cg = 0.f, ho = 0.f;
  float* outp = nullptr;
  float xr = 0.f;
  const float* xnext = nullptr;

  if (isw) {
#pragma unroll
    for (int j = 0; j < 4; ++j) {
      const int base = n * 512 + 128 * j + 16 * w + quad * 4;
      const f32x4 b1 = *(const f32x4*)(bih + base);
      const f32x4 b2 = *(const f32x4*)(bhh + base);
#pragma unroll
      for (int r = 0; r < 4; ++r) cb[j][r] = b1[r] + b2[r];
    }
    if (tid < 256) {
      const int bi = tid >> 6, j2 = (tid & 63) * 2;
      const f32x2 hv = *(const f32x2*)(h0 + (size_t)(4 * bg + bi) * 4096 + n * 128 + j2);
      *(uint32_t*)&hbuf[0][bi * 144 + j2] =
          (uint32_t)(uint16_t)f2bf(hv[0]) | ((uint32_t)(uint16_t)f2bf(hv[1]) << 16);
    }
    cg = c0[(size_t)b * 4096 + n * 128 + hgl];
    outp = out + (size_t)b * (TSTEPS * 4096) + n * 128 + hgl;
  } else if (tid < 768) {
    const int bq = (tid >> 6) & 3;
    const int kq = tid & 63;
    const float* xp = x + (size_t)(4 * bg + bq) * (TSTEPS * 2048) + n * 64 + kq;
    xbuf[1][bq * 96 + kq] = f2bf(xp[2048]);
    xr = xp[2 * 2048];
    xnext = xp + 3 * 2048;
  }
  __syncthreads();

  if (isw) {
#define WSTEPF(CUR, NXT, S)                                                  \
  {                                                                          \
    Frag hf0;                                                                \
    hf0.s = *(const s16x8*)&hbuf[CUR][hoff];                                 \
    f32x4 ac1[4];                                                            \
    _Pragma("unroll") for (int j = 0; j < 4; ++j)                            \
      ac1[j] = mf(wfr[2][j], hf0, acpre[j]);                                 \
    float pre[4];                                                            \
    _Pragma("unroll") for (int j = 0; j < 4; ++j)                            \
      pre[j] = sel4(ac1[j], m1, m2);                                         \
    sync_lds();                                                              \
    const f32x4 vv = *(const f32x4*)&pbuf[w][lane][0];                       \
    pre[0] += vv[0]; pre[1] += vv[1]; pre[2] += vv[2]; pre[3] += vv[3];      \
    const float si = sig2(KSIG * pre[0]);                                    \
    const float sf = sig2(KSIG * pre[1]);                                    \
    const float sg = sig2(KTAN * pre[2]);                                    \
    const float so = sig2(KSIG * pre[3]);                                    \
    float cn = __builtin_fmaf(sf, cg, si);                                   \
    cn = __builtin_fmaf(-2.f, si * sg, cn);                                  \
    cg = cn;                                                                 \
    ho = so * __builtin_fmaf(-2.f, sig2(KTAN * cn), 1.f);                    \
    hbuf[NXT][hwoff] = f2bf(ho);                                             \
    *outp = ho;                                                              \
    outp += 4096;                                                            \
    Frag xg0, xg1;                                                           \
    xg0.s = *(const s16x8*)&xbuf[NXT][xoff];                                 \
    xg1.s = *(const s16x8*)&xbuf[NXT][xoff + 32];                            \
    _Pragma("unroll") for (int j = 0; j < 4; ++j)                            \
      acpre[j] = mf(wfr[0][j], xg0, cb[j]);                                  \
    _Pragma("unroll") for (int j = 0; j < 4; ++j)                            \
      acpre[j] = mf(wfr[1][j], xg1, acpre[j]);                               \
    sync_lds();                                                              \
  }
    {
      const float* q = x + (size_t)b * (TSTEPS * 2048) + n * 64 + 8 * quad;
      const f32x4 a0 = *(const f32x4*)q;
      const f32x4 a1 = *(const f32x4*)(q + 4);
      const f32x4 a2 = *(const f32x4*)(q + 32);
      const f32x4 a3 = *(const f32x4*)(q + 36);
      Frag xf0, xf1;
#pragma unroll
      for (int r = 0; r < 4; ++r) {
        xf0.s[r]     = f2bf(a0[r]);
        xf0.s[4 + r] = f2bf(a1[r]);
        xf1.s[r]     = f2bf(a2[r]);
        xf1.s[4 + r] = f2bf(a3[r]);
      }
#pragma unroll
      for (int j = 0; j < 4; ++j)
        acpre[j] = mf(wfr[1][j], xf1, mf(wfr[0][j], xf0, cb[j]));
    }
    for (int t = 0; t < TSTEPS; t += 2) {
      WSTEPF(0, 1, t);
      WSTEPF(1, 0, t + 1);
    }
#undef WSTEPF
    out[16777216 +         (size_t)b * 4096 + n * 128 + hgl] = ho;
    out[16777216 + 65536 + (size_t)b * 4096 + n * 128 + hgl] = cg;
  } else {
    const int sxoff = ((tid >> 6) & 3) * 96 + (tid & 63);
    const bool stg = (tid < 768);
#define VSTEPF(CUR, NXT, S)                                                  \
  {                                                                          \
    Frag hf1, hf2, hf3;                                                      \
    hf1.s = *(const s16x8*)&hbuf[CUR][hoff + 32];                            \
    hf2.s = *(const s16x8*)&hbuf[CUR][hoff + 64];                            \
    hf3.s = *(const s16x8*)&hbuf[CUR][hoff + 96];                            \
    if (stg) {                                                               \
      xbuf[CUR][sxoff] = f2bf(xr);                                           \
      if ((S) + 3 < TSTEPS) { xr = *xnext; xnext += 2048; }                  \
    }                                                                        \
    f32x4 ac[4];                                                             \
    _Pragma("unroll") for (int j = 0; j < 4; ++j)                            \
      ac[j] = mf(wfr[0][j], hf1, kzero);                                     \
    _Pragma("unroll") for (int j = 0; j < 4; ++j)                            \
      ac[j] = mf(wfr[1][j], hf2, ac[j]);                                     \
    _Pragma("unroll") for (int j = 0; j < 4; ++j)                            \
      ac[j] = mf(wfr[2][j], hf3, ac[j]);                                     \
    f32x4 vv;                                                                \
    vv[0] = sel4(ac[0], m1, m2);                                             \
    vv[1] = sel4(ac[1], m1, m2);                                             \
    vv[2] = sel4(ac[2], m1, m2);                                             \
    vv[3] = sel4(ac[3], m1, m2);                                             \
    *(f32x4*)&pbuf[w][lane][0] = vv;                                         \
    sync_lds();                                                              \
    sync_lds();                                                              \
  }
    {
      const float* q = x + (size_t)b * (TSTEPS * 2048) + n * 64 + 8 * quad;
      (void)q;
    }
    for (int t = 0; t < TSTEPS; t += 2) {
      VSTEPF(0, 1, t);
      VSTEPF(1, 0, t + 1);
    }
#undef VSTEPF
  }
}

extern "C" void kernel_launch(void* const* d_in, const int* in_sizes, int n_in,
                              void* d_out, int out_size, void* d_ws, size_t ws_size,
                              hipStream_t stream) {
  const float* x   = (const float*)d_in[0];
  const float* h0  = (const float*)d_in[1];
  const float* c0  = (const float*)d_in[2];
  const float* wih = (const float*)d_in[3];
  const float* whh = (const float*)d_in[4];
  const float* bih = (const float*)d_in[5];
  const float* bhh = (const float*)d_in[6];
  float* out = (float*)d_out;
  const size_t need = (size_t)512 * 256 * 512 * 4;   // 268,435,456 B
  if (ws_size >= need && d_ws != nullptr) {
    float* gxw = (float*)d_ws;
    gx_gemm<<<512, 512, 0, stream>>>(x, wih, bih, bhh, gxw);
    wide_lstm_pc<<<128, 1024, 0, stream>>>(h0, c0, whh, gxw, out);
  } else {
    wide_lstm_fb<<<128, 1024, 0, stream>>>(x, h0, c0, wih, whh, bih, bhh, out);
  }
}